// Round 2
// baseline (1762.956 us; speedup 1.0000x reference)
//
#include <hip/hip_runtime.h>
#include <math.h>

#define H_   8
#define DIN  128
#define DK   16
#define DV   16
#define DE   128
#define B_   128
#define N_   256
#define NORMC 0.25f

// ---------------------------------------------------------------------------
// Kernel 1: per-head Q/K/V projections.
// grid = (B*N/256, H), block = 256. One thread per row (b*N+n), one head per
// blockIdx.y. Weights (128x16 x3 = 24KB) staged in LDS; all LDS reads are
// wave-uniform broadcasts.
// ---------------------------------------------------------------------------
__global__ __launch_bounds__(256) void qkv_kernel(
    const float* __restrict__ qin, const float* __restrict__ hin,
    const float* __restrict__ Wq, const float* __restrict__ Wk,
    const float* __restrict__ Wv, float* __restrict__ Q,
    float* __restrict__ K, float* __restrict__ V) {
  const int h = blockIdx.y;
  const int row = blockIdx.x * 256 + threadIdx.x;  // b*N + n
  __shared__ float wq[DIN * DK], wk[DIN * DK], wv[DIN * DK];
  for (int idx = threadIdx.x; idx < DIN * DK; idx += 256) {
    wq[idx] = Wq[h * DIN * DK + idx];
    wk[idx] = Wk[h * DIN * DK + idx];
    wv[idx] = Wv[h * DIN * DK + idx];
  }
  __syncthreads();

  float aq[DK], ak[DK], av[DK];
#pragma unroll
  for (int k = 0; k < DK; ++k) { aq[k] = 0.f; ak[k] = 0.f; av[k] = 0.f; }

  const float4* qrow = reinterpret_cast<const float4*>(qin + (size_t)row * DIN);
  const float4* hrow = reinterpret_cast<const float4*>(hin + (size_t)row * DIN);
  for (int d4 = 0; d4 < DIN / 4; ++d4) {
    const float4 qv = qrow[d4];
    const float4 hv = hrow[d4];
    const int d = d4 * 4;
#pragma unroll
    for (int k = 0; k < DK; ++k) {
      aq[k] += qv.x * wq[(d + 0) * DK + k] + qv.y * wq[(d + 1) * DK + k] +
               qv.z * wq[(d + 2) * DK + k] + qv.w * wq[(d + 3) * DK + k];
      ak[k] += hv.x * wk[(d + 0) * DK + k] + hv.y * wk[(d + 1) * DK + k] +
               hv.z * wk[(d + 2) * DK + k] + hv.w * wk[(d + 3) * DK + k];
      av[k] += hv.x * wv[(d + 0) * DK + k] + hv.y * wv[(d + 1) * DK + k] +
               hv.z * wv[(d + 2) * DK + k] + hv.w * wv[(d + 3) * DK + k];
    }
  }
  const size_t o = ((size_t)h * B_ * N_ + (size_t)row) * DK;
#pragma unroll
  for (int k = 0; k < DK; ++k) { Q[o + k] = aq[k]; K[o + k] = ak[k]; V[o + k] = av[k]; }
}

// ---------------------------------------------------------------------------
// Kernel 2: fused edge-MLP + masked softmax attention + output projection.
// grid = B*N blocks (one per (b, query i)), block = 256 (one thread per key j).
// mask arrives as int32 (harness materializes bool as integer).
// ---------------------------------------------------------------------------
__global__ __launch_bounds__(256) void attn_kernel(
    const float* __restrict__ Q, const float* __restrict__ K,
    const float* __restrict__ V, const int* __restrict__ mask,
    const float* __restrict__ edge, const float* __restrict__ mw1,
    const float* __restrict__ mb1, const float* __restrict__ mw2,
    const float* __restrict__ mb2, const float* __restrict__ mw3,
    const float* __restrict__ mb3, const float* __restrict__ Wo,
    float* __restrict__ out) {
  const int t = threadIdx.x;
  const int bi = blockIdx.x;
  const int b = bi >> 8;   // N_ = 256
  const int i = bi & 255;

  __shared__ float smw1[16], smb1[16], smw2[256], smb2[16], smw3[128], smb3[8];
  __shared__ float qi[H_ * DK];
  __shared__ float P[H_][N_];
  __shared__ float redmax[H_][4];
  __shared__ float redsum[H_][4];
  __shared__ float4 part[H_][4][8];
  __shared__ float heads[H_ * DV];

  smw2[t] = mw2[t];
  if (t < 16) { smw1[t] = mw1[t]; smb1[t] = mb1[t]; smb2[t] = mb2[t]; }
  if (t < 128) smw3[t] = mw3[t];
  if (t < 8)  smb3[t] = mb3[t];
  if (t < H_ * DK)
    qi[t] = Q[((size_t)(t >> 4) * B_ * N_ + (size_t)b * N_ + i) * DK + (t & 15)];
  __syncthreads();

  // ---- Phase 1: edge MLP bias + QK^T score for key j = t -------------------
  const int j = t;
  const size_t rowij = (size_t)(b * N_ + i) * N_ + j;
  const int mv = mask[rowij];
  const float e = edge[rowij];

  float l1[16], l2[16];
#pragma unroll
  for (int a = 0; a < 16; ++a) l1[a] = fmaxf(fmaf(e, smw1[a], smb1[a]), 0.f);
#pragma unroll
  for (int c = 0; c < 16; ++c) {
    float acc = smb2[c];
#pragma unroll
    for (int a = 0; a < 16; ++a) acc = fmaf(l1[a], smw2[a * 16 + c], acc);
    l2[c] = fmaxf(acc, 0.f);
  }
  float s[H_];
#pragma unroll
  for (int hh = 0; hh < H_; ++hh) s[hh] = smb3[hh];
#pragma unroll
  for (int c = 0; c < 16; ++c) {
#pragma unroll
    for (int hh = 0; hh < H_; ++hh) s[hh] = fmaf(l2[c], smw3[c * H_ + hh], s[hh]);
  }

  const float4* Kp = reinterpret_cast<const float4*>(K);
#pragma unroll
  for (int hh = 0; hh < H_; ++hh) {
    const size_t kb = ((size_t)hh * B_ * N_ + (size_t)b * N_ + j) * (DK / 4);
    const float4 k0 = Kp[kb + 0], k1 = Kp[kb + 1], k2 = Kp[kb + 2], k3 = Kp[kb + 3];
    const float* qh = &qi[hh * DK];
    float dot = qh[0] * k0.x + qh[1] * k0.y + qh[2] * k0.z + qh[3] * k0.w +
                qh[4] * k1.x + qh[5] * k1.y + qh[6] * k1.z + qh[7] * k1.w +
                qh[8] * k2.x + qh[9] * k2.y + qh[10] * k2.z + qh[11] * k2.w +
                qh[12] * k3.x + qh[13] * k3.y + qh[14] * k3.z + qh[15] * k3.w;
    s[hh] = NORMC * dot + s[hh];
    if (mv) s[hh] = -INFINITY;
  }

  // ---- Softmax over j (per head): block reduce max then sum ---------------
#pragma unroll
  for (int hh = 0; hh < H_; ++hh) {
    float m = s[hh];
    for (int off = 32; off > 0; off >>= 1) m = fmaxf(m, __shfl_down(m, off, 64));
    if ((t & 63) == 0) redmax[hh][t >> 6] = m;
  }
  __syncthreads();
  float p[H_];
#pragma unroll
  for (int hh = 0; hh < H_; ++hh) {
    const float m = fmaxf(fmaxf(redmax[hh][0], redmax[hh][1]),
                          fmaxf(redmax[hh][2], redmax[hh][3]));
    float pv = (mv || m == -INFINITY) ? 0.f : __expf(s[hh] - m);
    p[hh] = pv;
    float sum = pv;
    for (int off = 32; off > 0; off >>= 1) sum += __shfl_down(sum, off, 64);
    if ((t & 63) == 0) redsum[hh][t >> 6] = sum;
  }
  __syncthreads();
#pragma unroll
  for (int hh = 0; hh < H_; ++hh) {
    const float sum = redsum[hh][0] + redsum[hh][1] + redsum[hh][2] + redsum[hh][3];
    P[hh][j] = sum > 0.f ? p[hh] / sum : 0.f;
  }
  __syncthreads();

  // ---- Phase 2: heads[h,:] = sum_j P[h,j] * V[h,b,j,:] --------------------
  // t -> (head h2, float4 group v4, j-slice jsl). j interleaved (jx=jj*8+jsl)
  // so the 16 distinct P addresses per iteration hit 8 banks (2-way = free).
  {
    const int h2 = t >> 5;
    const int g = t & 31;
    const int v4 = g & 3;
    const int jsl = g >> 2;
    const float4* Vp = reinterpret_cast<const float4*>(V);
    const size_t vbase = ((size_t)h2 * B_ * N_ + (size_t)b * N_) * 4;
    float4 acc = make_float4(0.f, 0.f, 0.f, 0.f);
    for (int jj = 0; jj < 32; ++jj) {
      const int jx = jj * 8 + jsl;
      const float pj = P[h2][jx];
      const float4 vv = Vp[vbase + (size_t)jx * 4 + v4];
      acc.x = fmaf(pj, vv.x, acc.x);
      acc.y = fmaf(pj, vv.y, acc.y);
      acc.z = fmaf(pj, vv.z, acc.z);
      acc.w = fmaf(pj, vv.w, acc.w);
    }
    part[h2][v4][jsl] = acc;
  }
  __syncthreads();
  if (t < 32) {
    const int hh = t >> 2, vq = t & 3;
    float4 sacc = part[hh][vq][0];
#pragma unroll
    for (int r = 1; r < 8; ++r) {
      const float4 pz = part[hh][vq][r];
      sacc.x += pz.x; sacc.y += pz.y; sacc.z += pz.z; sacc.w += pz.w;
    }
    heads[hh * DV + vq * 4 + 0] = sacc.x;
    heads[hh * DV + vq * 4 + 1] = sacc.y;
    heads[hh * DV + vq * 4 + 2] = sacc.z;
    heads[hh * DV + vq * 4 + 3] = sacc.w;
  }
  __syncthreads();

  // ---- Phase 3: out[b,i,e] = sum_{h,v} heads[h,v] * Wo[h,v,e] -------------
  if (t < DE) {
    float acc = 0.f;
#pragma unroll 16
    for (int hv = 0; hv < H_ * DV; ++hv)
      acc = fmaf(heads[hv], Wo[hv * DE + t], acc);
    out[((size_t)(b * N_ + i)) * DE + t] = acc;
  }
}

extern "C" void kernel_launch(void* const* d_in, const int* in_sizes, int n_in,
                              void* d_out, int out_size, void* d_ws, size_t ws_size,
                              hipStream_t stream) {
  const float* q    = (const float*)d_in[0];
  const float* hm   = (const float*)d_in[1];
  const int* mask   = (const int*)d_in[2];   // bool materialized as int32
  const float* edge = (const float*)d_in[3];
  const float* Wq   = (const float*)d_in[4];
  const float* Wk   = (const float*)d_in[5];
  const float* Wv   = (const float*)d_in[6];
  const float* Wo   = (const float*)d_in[7];
  const float* mw1  = (const float*)d_in[8];
  const float* mb1  = (const float*)d_in[9];
  const float* mw2  = (const float*)d_in[10];
  const float* mb2  = (const float*)d_in[11];
  const float* mw3  = (const float*)d_in[12];
  const float* mb3  = (const float*)d_in[13];
  float* out = (float*)d_out;

  float* ws = (float*)d_ws;
  const size_t per = (size_t)H_ * B_ * N_ * DK;  // 4,194,304 floats
  float* Q = ws;
  float* K = ws + per;
  float* V = ws + 2 * per;

  qkv_kernel<<<dim3(B_ * N_ / 256, H_), 256, 0, stream>>>(q, hm, Wq, Wk, Wv, Q, K, V);
  attn_kernel<<<dim3(B_ * N_), 256, 0, stream>>>(Q, K, V, mask, edge, mw1, mb1,
                                                 mw2, mb2, mw3, mb3, Wo, out);
}